// Round 4
// baseline (306.833 us; speedup 1.0000x reference)
//
#include <hip/hip_runtime.h>

#define NN 50000          // nodes
#define NE 800000         // edges (without self loops)
#define F  96             // feature dim
#define RB4 12            // 16B chunks per 96-feature row
#define OD 32             // output dim
#define NG 256            // graphs
#define CAP 64            // bucket capacity per node
#define PROWS 21          // node rows in pool block
#define SHARDS 8
#define SHARD_SZ 6250
#define PERSHARD 64
#define NWF 1152          // W-fragment uint4 count: 6 ct * 3 kc * 4 quad * 16 n
#define RPB 64            // rows per MFMA block
#define NB64 782          // ceil(NN/64) node tiles
#define PL   (NN * 16)    // plane stride in u32 (64B per node per plane)
#define PLH  (NN * 32)    // plane stride in u16
#define PL2  (NN * 8)     // plane stride in uint2
#define AGG_GRID 2048     // 256 stripes x 8 XCD slots, fully co-resident

typedef unsigned int u32;
typedef unsigned short u16;
typedef short short8 __attribute__((ext_vector_type(8)));   // 8 bf16 (4 VGPRs)
typedef float f32x4 __attribute__((ext_vector_type(4)));
typedef unsigned int u32x4 __attribute__((ext_vector_type(4)));
typedef unsigned int u32x2 __attribute__((ext_vector_type(2)));

static inline size_t align_up(size_t x) { return (x + 255) & ~(size_t)255; }

// ---- bf16 helpers (RNE) ----
__device__ inline u32 f2bf_rne(float x) {
    u32 u = __float_as_uint(x);
    return (u + 0x7fffu + ((u >> 16) & 1u)) >> 16;
}
__device__ inline u32 packbf(float a, float b) {
    return f2bf_rne(a) | (f2bf_rne(b) << 16);
}
__device__ inline float bf_lo(u32 u) { return __uint_as_float(u << 16); }
__device__ inline float bf_hi(u32 u) { return __uint_as_float(u & 0xffff0000u); }

// ---------------- pack edges: ep[e] = tgt<<16 | src (ids < 65536) ----------------
__global__ __launch_bounds__(256) void k_pack(const int* __restrict__ src,
                                              const int* __restrict__ tgt,
                                              uint4* __restrict__ ep4) {
    int c = blockIdx.x * 256 + threadIdx.x;
    if (c >= NE / 4) return;
    int4 s4 = reinterpret_cast<const int4*>(src)[c];
    int4 t4 = reinterpret_cast<const int4*>(tgt)[c];
    ep4[c] = make_uint4(((u32)t4.x << 16) | (u32)s4.x, ((u32)t4.y << 16) | (u32)s4.y,
                        ((u32)t4.z << 16) | (u32)s4.z, ((u32)t4.w << 16) | (u32)s4.w);
}

// ---------------- sharded bucket fill from packed edges ----------------
__global__ __launch_bounds__(256) void k_fillb(const uint4* __restrict__ ep4,
                                               int* __restrict__ cnt,
                                               u16* __restrict__ bucket) {
    int shard = blockIdx.x & (SHARDS - 1);
    int sb    = blockIdx.x >> 3;
    int lo    = shard * SHARD_SZ;
    int hi    = lo + SHARD_SZ;
    const int nchunk = NE / 4;
    for (int c = sb * 256 + threadIdx.x; c < nchunk; c += PERSHARD * 256) {
        uint4 p = ep4[c];
        int t0 = p.x >> 16, s0 = p.x & 0xffff;
        int t1 = p.y >> 16, s1 = p.y & 0xffff;
        int t2 = p.z >> 16, s2 = p.z & 0xffff;
        int t3 = p.w >> 16, s3 = p.w & 0xffff;
        if (t0 >= lo && t0 < hi) {
            int q = atomicAdd(&cnt[t0], 1);
            if (q < CAP) bucket[t0 * CAP + q] = (u16)s0;
        }
        if (t1 >= lo && t1 < hi) {
            int q = atomicAdd(&cnt[t1], 1);
            if (q < CAP) bucket[t1 * CAP + q] = (u16)s1;
        }
        if (t2 >= lo && t2 < hi) {
            int q = atomicAdd(&cnt[t2], 1);
            if (q < CAP) bucket[t2 * CAP + q] = (u16)s2;
        }
        if (t3 >= lo && t3 < hi) {
            int q = atomicAdd(&cnt[t3], 1);
            if (q < CAP) bucket[t3 * CAP + q] = (u16)s3;
        }
    }
}

// ---------------- fused: dis = rsqrt(cnt+1); r0 = dis[v]*x[v] -> plane layout ----
// plane g (g=0..2) holds features [32g,32g+32) of all nodes: 64B/node, 3.2MB.
__global__ __launch_bounds__(256) void k_cvt(const float4* __restrict__ x4,
                                             const int* __restrict__ cnt,
                                             float* __restrict__ dis,
                                             u32* __restrict__ rb) {
    int i = blockIdx.x * 256 + threadIdx.x;
    if (i >= NN * RB4) return;
    int v   = i / RB4;
    int sub = i - v * RB4;
    float dv = rsqrtf((float)(cnt[v] + 1));   // +1 self loop
    if (sub == 0) dis[v] = dv;
    float4 f0 = x4[(size_t)i * 2];
    float4 f1 = x4[(size_t)i * 2 + 1];
    u32x4 r;
    r[0] = packbf(dv * f0.x, dv * f0.y);
    r[1] = packbf(dv * f0.z, dv * f0.w);
    r[2] = packbf(dv * f1.x, dv * f1.y);
    r[3] = packbf(dv * f1.z, dv * f1.w);
    int g = sub >> 2;
    int j = sub & 3;
    *reinterpret_cast<u32x4*>(&rb[(size_t)g * PL + (size_t)v * 16 + j * 4]) = r;
}

// ---------------- all three W (fp32 96x96) -> MFMA B-fragment layout ----------------
__global__ __launch_bounds__(256) void k_wprep3(const float* __restrict__ W1,
                                                const float* __restrict__ W2,
                                                const float* __restrict__ W3,
                                                uint4* __restrict__ wf) {
    int e = blockIdx.x * 256 + threadIdx.x;
    if (e >= 3 * NWF) return;
    int wi = e / NWF;
    int f  = e - wi * NWF;
    const float* W = (wi == 0) ? W1 : ((wi == 1) ? W2 : W3);
    int n  = f & 15;
    int t1 = f >> 4;
    int quad = t1 & 3;
    int t2 = t1 >> 2;
    int kc = t2 % 3;
    int ct = t2 / 3;
    int k  = kc * 32 + quad * 8;
    int col = ct * 16 + n;
    u32 w0 = packbf(W[(k + 0) * F + col], W[(k + 1) * F + col]);
    u32 w1 = packbf(W[(k + 2) * F + col], W[(k + 3) * F + col]);
    u32 w2 = packbf(W[(k + 4) * F + col], W[(k + 5) * F + col]);
    u32 w3 = packbf(W[(k + 6) * F + col], W[(k + 7) * F + col]);
    wf[e] = make_uint4(w0, w1, w2, w3);
}

// ---------------- XCD-affine aggregation over contiguous planes -----------------
// XCD slot {0,1,2}->plane0 {3,4,5}->plane1 {6,7}->plane2 (bid%8 ~ XCD RR).
// Each XCD's random-read set = one 3.2MB plane (contiguous -> 128B L2 lines stay
// in-plane). Bucket loads NT (no L2 allocate); aggb store NT (streamed out).
// Block: 256 thr = 64 nodes x 4 lanes; lane j handles 16B chunk j of the 64B.
__global__ __launch_bounds__(256, 8) void k_agg(const u32* __restrict__ rprev,
                                                const int* __restrict__ cnt,
                                                const u16* __restrict__ bucket,
                                                const float* __restrict__ dis,
                                                u32* __restrict__ aggb) {
    int s8     = blockIdx.x & 7;
    int stripe = blockIdx.x >> 3;
    int g  = (s8 * 3) >> 3;          // 0,0,0,1,1,1,2,2
    int w  = s8 - 3 * g;             // index within plane-group
    int S  = (g == 2) ? 2 : 3;       // slots serving this plane
    const u32* pl = rprev + (size_t)g * PL;
    u32*       po = aggb  + (size_t)g * PL;
    int nd = threadIdx.x >> 2;
    int j4 = (threadIdx.x & 3) << 2;  // u32 offset of 16B chunk within 64B

    for (int t = stripe * S + w; t < NB64; t += 256 * S) {
        int v = (t << 6) + nd;
        if (v < NN) {
            uint4 hv = *reinterpret_cast<const uint4*>(&pl[(size_t)v * 16 + j4]);
            float a0 = bf_lo(hv.x), a1 = bf_hi(hv.x);
            float a2 = bf_lo(hv.y), a3 = bf_hi(hv.y);
            float a4 = bf_lo(hv.z), a5 = bf_hi(hv.z);
            float a6 = bf_lo(hv.w), a7 = bf_hi(hv.w);   // self term r[v]

            int deg = cnt[v];
            if (deg > CAP) deg = CAP;
            const u16* bkt = &bucket[v * CAP];
            int e = 0;
            for (; e + 7 < deg; e += 8) {
                u32x4 b8 = __builtin_nontemporal_load(
                    reinterpret_cast<const u32x4*>(&bkt[e]));
                int s0 = b8[0] & 0xffff, s1 = b8[0] >> 16;
                int s2 = b8[1] & 0xffff, s3 = b8[1] >> 16;
                int s4 = b8[2] & 0xffff, s5 = b8[2] >> 16;
                int s6 = b8[3] & 0xffff, s7 = b8[3] >> 16;
                uint4 g0 = *reinterpret_cast<const uint4*>(&pl[(size_t)s0 * 16 + j4]);
                uint4 g1 = *reinterpret_cast<const uint4*>(&pl[(size_t)s1 * 16 + j4]);
                uint4 g2 = *reinterpret_cast<const uint4*>(&pl[(size_t)s2 * 16 + j4]);
                uint4 g3 = *reinterpret_cast<const uint4*>(&pl[(size_t)s3 * 16 + j4]);
                uint4 g4 = *reinterpret_cast<const uint4*>(&pl[(size_t)s4 * 16 + j4]);
                uint4 g5 = *reinterpret_cast<const uint4*>(&pl[(size_t)s5 * 16 + j4]);
                uint4 g6 = *reinterpret_cast<const uint4*>(&pl[(size_t)s6 * 16 + j4]);
                uint4 g7 = *reinterpret_cast<const uint4*>(&pl[(size_t)s7 * 16 + j4]);
                a0 += bf_lo(g0.x) + bf_lo(g1.x) + bf_lo(g2.x) + bf_lo(g3.x)
                    + bf_lo(g4.x) + bf_lo(g5.x) + bf_lo(g6.x) + bf_lo(g7.x);
                a1 += bf_hi(g0.x) + bf_hi(g1.x) + bf_hi(g2.x) + bf_hi(g3.x)
                    + bf_hi(g4.x) + bf_hi(g5.x) + bf_hi(g6.x) + bf_hi(g7.x);
                a2 += bf_lo(g0.y) + bf_lo(g1.y) + bf_lo(g2.y) + bf_lo(g3.y)
                    + bf_lo(g4.y) + bf_lo(g5.y) + bf_lo(g6.y) + bf_lo(g7.y);
                a3 += bf_hi(g0.y) + bf_hi(g1.y) + bf_hi(g2.y) + bf_hi(g3.y)
                    + bf_hi(g4.y) + bf_hi(g5.y) + bf_hi(g6.y) + bf_hi(g7.y);
                a4 += bf_lo(g0.z) + bf_lo(g1.z) + bf_lo(g2.z) + bf_lo(g3.z)
                    + bf_lo(g4.z) + bf_lo(g5.z) + bf_lo(g6.z) + bf_lo(g7.z);
                a5 += bf_hi(g0.z) + bf_hi(g1.z) + bf_hi(g2.z) + bf_hi(g3.z)
                    + bf_hi(g4.z) + bf_hi(g5.z) + bf_hi(g6.z) + bf_hi(g7.z);
                a6 += bf_lo(g0.w) + bf_lo(g1.w) + bf_lo(g2.w) + bf_lo(g3.w)
                    + bf_lo(g4.w) + bf_lo(g5.w) + bf_lo(g6.w) + bf_lo(g7.w);
                a7 += bf_hi(g0.w) + bf_hi(g1.w) + bf_hi(g2.w) + bf_hi(g3.w)
                    + bf_hi(g4.w) + bf_hi(g5.w) + bf_hi(g6.w) + bf_hi(g7.w);
            }
            for (; e + 3 < deg; e += 4) {
                u32x2 b4 = __builtin_nontemporal_load(
                    reinterpret_cast<const u32x2*>(&bkt[e]));
                int s0 = b4[0] & 0xffff, s1 = b4[0] >> 16;
                int s2 = b4[1] & 0xffff, s3 = b4[1] >> 16;
                uint4 g0 = *reinterpret_cast<const uint4*>(&pl[(size_t)s0 * 16 + j4]);
                uint4 g1 = *reinterpret_cast<const uint4*>(&pl[(size_t)s1 * 16 + j4]);
                uint4 g2 = *reinterpret_cast<const uint4*>(&pl[(size_t)s2 * 16 + j4]);
                uint4 g3 = *reinterpret_cast<const uint4*>(&pl[(size_t)s3 * 16 + j4]);
                a0 += bf_lo(g0.x) + bf_lo(g1.x) + bf_lo(g2.x) + bf_lo(g3.x);
                a1 += bf_hi(g0.x) + bf_hi(g1.x) + bf_hi(g2.x) + bf_hi(g3.x);
                a2 += bf_lo(g0.y) + bf_lo(g1.y) + bf_lo(g2.y) + bf_lo(g3.y);
                a3 += bf_hi(g0.y) + bf_hi(g1.y) + bf_hi(g2.y) + bf_hi(g3.y);
                a4 += bf_lo(g0.z) + bf_lo(g1.z) + bf_lo(g2.z) + bf_lo(g3.z);
                a5 += bf_hi(g0.z) + bf_hi(g1.z) + bf_hi(g2.z) + bf_hi(g3.z);
                a6 += bf_lo(g0.w) + bf_lo(g1.w) + bf_lo(g2.w) + bf_lo(g3.w);
                a7 += bf_hi(g0.w) + bf_hi(g1.w) + bf_hi(g2.w) + bf_hi(g3.w);
            }
            for (; e < deg; ++e) {
                int s = bkt[e];
                uint4 gg = *reinterpret_cast<const uint4*>(&pl[(size_t)s * 16 + j4]);
                a0 += bf_lo(gg.x); a1 += bf_hi(gg.x);
                a2 += bf_lo(gg.y); a3 += bf_hi(gg.y);
                a4 += bf_lo(gg.z); a5 += bf_hi(gg.z);
                a6 += bf_lo(gg.w); a7 += bf_hi(gg.w);
            }
            float dv = dis[v];
            u32x4 res;
            res[0] = packbf(dv * a0, dv * a1);
            res[1] = packbf(dv * a2, dv * a3);
            res[2] = packbf(dv * a4, dv * a5);
            res[3] = packbf(dv * a6, dv * a7);
            __builtin_nontemporal_store(res,
                reinterpret_cast<u32x4*>(&po[(size_t)v * 16 + j4]));
        }
    }
}

// ---------------- MFMA: rnext = post( aggb @ W + b ), plane in / plane out -------
__global__ __launch_bounds__(256) void k_mm(const u32* __restrict__ aggb,
                                            const uint4* __restrict__ wfragG,
                                            const float* __restrict__ dis,
                                            const float* __restrict__ bias,
                                            const int last,
                                            u16* __restrict__ rnext) {
    int tid  = threadIdx.x;
    int r0   = blockIdx.x * RPB;
    int wave = tid >> 6;
    int lane = tid & 63;
    int m    = lane & 15;
    int quad = lane >> 4;
    int arow = r0 + wave * 16 + m;
    bool rv  = arow < NN;

    // K-block kc == plane kc: 16B at plane kc + arow*64B + quad*16B
    short8 a0 = (short8)(short)0, a1 = (short8)(short)0, a2 = (short8)(short)0;
    if (rv) {
        size_t off = (size_t)arow * 16 + quad * 4;
        a0 = *reinterpret_cast<const short8*>(&aggb[0 * (size_t)PL + off]);
        a1 = *reinterpret_cast<const short8*>(&aggb[1 * (size_t)PL + off]);
        a2 = *reinterpret_cast<const short8*>(&aggb[2 * (size_t)PL + off]);
    }

    f32x4 acc[6];
#pragma unroll
    for (int ct = 0; ct < 6; ++ct) acc[ct] = (f32x4)(0.0f);
#pragma unroll
    for (int ct = 0; ct < 6; ++ct) {
        short8 b0 = *reinterpret_cast<const short8*>(&wfragG[((ct * 3 + 0) * 4 + quad) * 16 + m]);
        short8 b1 = *reinterpret_cast<const short8*>(&wfragG[((ct * 3 + 1) * 4 + quad) * 16 + m]);
        short8 b2 = *reinterpret_cast<const short8*>(&wfragG[((ct * 3 + 2) * 4 + quad) * 16 + m]);
        acc[ct] = __builtin_amdgcn_mfma_f32_16x16x32_bf16(a0, b0, acc[ct], 0, 0, 0);
        acc[ct] = __builtin_amdgcn_mfma_f32_16x16x32_bf16(a1, b1, acc[ct], 0, 0, 0);
        acc[ct] = __builtin_amdgcn_mfma_f32_16x16x32_bf16(a2, b2, acc[ct], 0, 0, 0);
    }

    // ---- epilogue: h = relu(y + b); store plane layout (last ? h : dis[row]*h) ----
    int rbase = r0 + wave * 16 + quad * 4;
    float dr[4];
#pragma unroll
    for (int r = 0; r < 4; ++r) {
        int row = rbase + r;
        dr[r] = (row < NN) ? (last ? 1.0f : dis[row]) : 0.0f;
    }
#pragma unroll
    for (int ct = 0; ct < 6; ++ct) {
        float bb = bias[ct * 16 + m];
        size_t pbase = (size_t)(ct >> 1) * PLH + (ct & 1) * 16 + m;
#pragma unroll
        for (int r = 0; r < 4; ++r) {
            int row = rbase + r;
            if (row < NN) {
                float h = fmaxf(acc[ct][r] + bb, 0.0f);
                rnext[pbase + (size_t)row * 32] = (u16)f2bf_rne(h * dr[r]);
            }
        }
    }
}

// ---------------- fused mean pool + FC per graph (batch is sorted) ----------------
__device__ inline int lower_bound_i(const int* __restrict__ a, int n, int key) {
    int lo = 0, hi = n;
    while (lo < hi) {
        int mid = (lo + hi) >> 1;
        if (a[mid] < key) lo = mid + 1; else hi = mid;
    }
    return lo;
}

__global__ __launch_bounds__(512) void k_poolfc(const uint2* __restrict__ hb2,
                                                const int* __restrict__ batch,
                                                const float* __restrict__ fcw,
                                                const float* __restrict__ fcb,
                                                float* __restrict__ out) {
    __shared__ int range[2];
    __shared__ float4 part[PROWS][24];
    __shared__ float pl[F];
    int g = blockIdx.x;
    int t = threadIdx.x;
    if (t == 0) range[0] = lower_bound_i(batch, NN, g);
    if (t == 1) range[1] = lower_bound_i(batch, NN, g + 1);
    __syncthreads();
    int lo = range[0], hi = range[1];
    int row = t / 24;
    int sub = t - row * 24;
    if (row < PROWS) {
        // sub covers features [4*sub, 4*sub+4): plane = sub>>3, uint2 idx = sub&7
        const uint2* pp = hb2 + (size_t)(sub >> 3) * PL2 + (sub & 7);
        float4 acc = make_float4(0.f, 0.f, 0.f, 0.f);
        for (int v = lo + row; v < hi; v += PROWS) {
            uint2 xv = pp[(size_t)v * 8];
            acc.x += bf_lo(xv.x); acc.y += bf_hi(xv.x);
            acc.z += bf_lo(xv.y); acc.w += bf_hi(xv.y);
        }
        part[row][sub] = acc;
    }
    __syncthreads();
    if (t < 24) {
        float4 s = part[0][t];
        for (int r = 1; r < PROWS; ++r) {
            float4 p = part[r][t];
            s.x += p.x; s.y += p.y; s.z += p.z; s.w += p.w;
        }
        float inv = 1.0f / fmaxf((float)(hi - lo), 1.0f);
        pl[t * 4 + 0] = s.x * inv;
        pl[t * 4 + 1] = s.y * inv;
        pl[t * 4 + 2] = s.z * inv;
        pl[t * 4 + 3] = s.w * inv;
    }
    __syncthreads();
    if (t < OD) {
        float acc = 0.0f;
        for (int f = 0; f < F; ++f) acc += pl[f] * fcw[f * OD + t];
        out[g * OD + t] = acc + fcb[t];
    }
}

extern "C" void kernel_launch(void* const* d_in, const int* in_sizes, int n_in,
                              void* d_out, int out_size, void* d_ws, size_t ws_size,
                              hipStream_t stream) {
    (void)in_sizes; (void)n_in; (void)out_size; (void)ws_size;
    const float* x    = (const float*)d_in[0];
    const int*   ei   = (const int*)d_in[1];
    const int*   batc = (const int*)d_in[2];
    const float* W1   = (const float*)d_in[3];
    const float* b1   = (const float*)d_in[4];
    const float* W2   = (const float*)d_in[5];
    const float* b2   = (const float*)d_in[6];
    const float* W3   = (const float*)d_in[7];
    const float* b3   = (const float*)d_in[8];
    const float* fcw  = (const float*)d_in[9];
    const float* fcb  = (const float*)d_in[10];
    float* out = (float*)d_out;

    const int* src = ei;
    const int* tgt = ei + NE;

    char* ws = (char*)d_ws;
    int*    cnt    = (int*)ws;    ws += align_up((size_t)NN * 4);
    float*  dis    = (float*)ws;  ws += align_up((size_t)NN * 4);
    u16*    bucket = (u16*)ws;    ws += align_up((size_t)NN * CAP * 2);   // 6.4 MB
    u32*    ep     = (u32*)ws;    ws += align_up((size_t)NE * 4);         // 3.2 MB
    u32*    rA     = (u32*)ws;    ws += align_up((size_t)3 * PL * 4);     // 9.6 MB
    u32*    rB     = (u32*)ws;    ws += align_up((size_t)3 * PL * 4);     // 9.6 MB
    u32*    rC     = (u32*)ws;    ws += align_up((size_t)3 * PL * 4);     // 9.6 MB (agg)
    uint4*  wfrag3 = (uint4*)ws;  ws += align_up((size_t)3 * NWF * 16);   // 55 KB

    const int B = 256;
    const int cvt_grid   = (NN * RB4 + B - 1) / B;
    const int wprep_grid = (3 * NWF + B - 1) / B;
    const int pack_grid  = (NE / 4 + B - 1) / B;
    const int mm_grid    = (NN + RPB - 1) / RPB;     // 782

    // ---- bucket build + prep (once per call) ----
    (void)hipMemsetAsync(cnt, 0, (size_t)NN * 4, stream);
    k_pack  <<<pack_grid, B, 0, stream>>>(src, tgt, (uint4*)ep);
    k_fillb <<<SHARDS * PERSHARD, B, 0, stream>>>((const uint4*)ep, cnt, bucket);
    k_wprep3<<<wprep_grid, B, 0, stream>>>(W1, W2, W3, wfrag3);
    k_cvt   <<<cvt_grid, B, 0, stream>>>((const float4*)x, cnt, dis, rA);

    // ---- 3 layers: XCD-affine plane gather/aggregate, then lean MFMA ----
    k_agg<<<AGG_GRID, B, 0, stream>>>(rA, cnt, bucket, dis, rC);
    k_mm <<<mm_grid, B, 0, stream>>>(rC, wfrag3 + 0 * NWF, dis, b1, 0, (u16*)rB);

    k_agg<<<AGG_GRID, B, 0, stream>>>(rB, cnt, bucket, dis, rC);
    k_mm <<<mm_grid, B, 0, stream>>>(rC, wfrag3 + 1 * NWF, dis, b2, 0, (u16*)rA);

    k_agg<<<AGG_GRID, B, 0, stream>>>(rA, cnt, bucket, dis, rC);
    k_mm <<<mm_grid, B, 0, stream>>>(rC, wfrag3 + 2 * NWF, dis, b3, 1, (u16*)rB);

    // ---- fused mean pool + FC ----
    k_poolfc<<<NG, 512, 0, stream>>>((const uint2*)rB, batc, fcw, fcb, out);
}

// Round 5
// 245.590 us; speedup vs baseline: 1.2494x; 1.2494x over previous
//
#include <hip/hip_runtime.h>

#define NN 50000          // nodes
#define NE 800000         // edges (without self loops)
#define F  96             // feature dim
#define FB 48             // u32 (bf16-pair) per bf16 row
#define RB4 12            // uint4 per bf16 row
#define OD 32             // output dim
#define NG 256            // graphs
#define CAP 64            // bucket capacity per node
#define PROWS 21          // node rows in pool block
#define SHARDS 8
#define SHARD_SZ 6250
#define PERSHARD 64
#define NWF 1152          // W-fragment uint4 count: 6 ct * 3 kc * 4 quad * 16 n
#define RPB 64            // rows per fused-layer block
#define TPB 256           // threads per fused-layer block (4 waves)

typedef unsigned int u32;
typedef unsigned short u16;
typedef short short8 __attribute__((ext_vector_type(8)));   // 8 bf16 (4 VGPRs)
typedef float f32x4 __attribute__((ext_vector_type(4)));
typedef unsigned int u32x4 __attribute__((ext_vector_type(4)));

static inline size_t align_up(size_t x) { return (x + 255) & ~(size_t)255; }

// ---- bf16 helpers (RNE) ----
__device__ inline u32 f2bf_rne(float x) {
    u32 u = __float_as_uint(x);
    return (u + 0x7fffu + ((u >> 16) & 1u)) >> 16;
}
__device__ inline u32 packbf(float a, float b) {
    return f2bf_rne(a) | (f2bf_rne(b) << 16);
}
__device__ inline float bf_lo(u32 u) { return __uint_as_float(u << 16); }
__device__ inline float bf_hi(u32 u) { return __uint_as_float(u & 0xffff0000u); }

// ---- device-scope (L1-bypass) 16B gather load: issue only; caller must
// s_waitcnt vmcnt(0) + sched_barrier(0) before consuming the result ----
__device__ inline u32x4 ld16_sc0(const u32* p) {
    u32x4 r;
    asm volatile("global_load_dwordx4 %0, %1, off sc0"
                 : "=v"(r) : "v"(p) : "memory");
    return r;
}
__device__ inline void gather_fence() {
    asm volatile("s_waitcnt vmcnt(0)" ::: "memory");
    __builtin_amdgcn_sched_barrier(0);
}

// ---------------- pack edges: ep[e] = tgt<<16 | src (ids < 65536) ----------------
__global__ __launch_bounds__(256) void k_pack(const int* __restrict__ src,
                                              const int* __restrict__ tgt,
                                              uint4* __restrict__ ep4) {
    int c = blockIdx.x * 256 + threadIdx.x;
    if (c >= NE / 4) return;
    int4 s4 = reinterpret_cast<const int4*>(src)[c];
    int4 t4 = reinterpret_cast<const int4*>(tgt)[c];
    ep4[c] = make_uint4(((u32)t4.x << 16) | (u32)s4.x, ((u32)t4.y << 16) | (u32)s4.y,
                        ((u32)t4.z << 16) | (u32)s4.z, ((u32)t4.w << 16) | (u32)s4.w);
}

// ---------------- sharded bucket fill from packed edges ----------------
__global__ __launch_bounds__(256) void k_fillb(const uint4* __restrict__ ep4,
                                               int* __restrict__ cnt,
                                               u16* __restrict__ bucket) {
    int shard = blockIdx.x & (SHARDS - 1);
    int sb    = blockIdx.x >> 3;
    int lo    = shard * SHARD_SZ;
    int hi    = lo + SHARD_SZ;
    const int nchunk = NE / 4;
    for (int c = sb * 256 + threadIdx.x; c < nchunk; c += PERSHARD * 256) {
        uint4 p = ep4[c];
        int t0 = p.x >> 16, s0 = p.x & 0xffff;
        int t1 = p.y >> 16, s1 = p.y & 0xffff;
        int t2 = p.z >> 16, s2 = p.z & 0xffff;
        int t3 = p.w >> 16, s3 = p.w & 0xffff;
        if (t0 >= lo && t0 < hi) {
            int q = atomicAdd(&cnt[t0], 1);
            if (q < CAP) bucket[t0 * CAP + q] = (u16)s0;
        }
        if (t1 >= lo && t1 < hi) {
            int q = atomicAdd(&cnt[t1], 1);
            if (q < CAP) bucket[t1 * CAP + q] = (u16)s1;
        }
        if (t2 >= lo && t2 < hi) {
            int q = atomicAdd(&cnt[t2], 1);
            if (q < CAP) bucket[t2 * CAP + q] = (u16)s2;
        }
        if (t3 >= lo && t3 < hi) {
            int q = atomicAdd(&cnt[t3], 1);
            if (q < CAP) bucket[t3 * CAP + q] = (u16)s3;
        }
    }
}

// ---------------- fused: dis = rsqrt(cnt+1); r0 = dis[v]*x[v] (bf16 rows) --------
__global__ __launch_bounds__(256) void k_cvt(const float4* __restrict__ x4,
                                             const int* __restrict__ cnt,
                                             float* __restrict__ dis,
                                             uint4* __restrict__ rb4) {
    int i = blockIdx.x * 256 + threadIdx.x;
    if (i >= NN * RB4) return;
    int v   = i / RB4;
    int sub = i - v * RB4;
    float dv = rsqrtf((float)(cnt[v] + 1));   // +1 self loop
    if (sub == 0) dis[v] = dv;
    float4 f0 = x4[(size_t)i * 2];
    float4 f1 = x4[(size_t)i * 2 + 1];
    rb4[i] = make_uint4(packbf(dv * f0.x, dv * f0.y), packbf(dv * f0.z, dv * f0.w),
                        packbf(dv * f1.x, dv * f1.y), packbf(dv * f1.z, dv * f1.w));
}

// ---------------- all three W (fp32 96x96) -> MFMA B-fragment layout ----------------
__global__ __launch_bounds__(256) void k_wprep3(const float* __restrict__ W1,
                                                const float* __restrict__ W2,
                                                const float* __restrict__ W3,
                                                uint4* __restrict__ wf) {
    int e = blockIdx.x * 256 + threadIdx.x;
    if (e >= 3 * NWF) return;
    int wi = e / NWF;
    int f  = e - wi * NWF;
    const float* W = (wi == 0) ? W1 : ((wi == 1) ? W2 : W3);
    int n  = f & 15;
    int t1 = f >> 4;
    int quad = t1 & 3;
    int t2 = t1 >> 2;
    int kc = t2 % 3;
    int ct = t2 / 3;
    int k  = kc * 32 + quad * 8;
    int col = ct * 16 + n;
    u32 w0 = packbf(W[(k + 0) * F + col], W[(k + 1) * F + col]);
    u32 w1 = packbf(W[(k + 2) * F + col], W[(k + 3) * F + col]);
    u32 w2 = packbf(W[(k + 4) * F + col], W[(k + 5) * F + col]);
    u32 w3 = packbf(W[(k + 6) * F + col], W[(k + 7) * F + col]);
    wf[e] = make_uint4(w0, w1, w2, w3);
}

// ---------------- fused GCN layer: rnext = post( agg(rprev) @ W + b ) -------------
__global__ __launch_bounds__(TPB) void k_layer(const uint4* __restrict__ rprev,
                                               const uint4* __restrict__ wfragG,
                                               const int* __restrict__ cnt,
                                               const u16* __restrict__ bucket,
                                               const float* __restrict__ dis,
                                               const float* __restrict__ bias,
                                               const int last,
                                               u16* __restrict__ rnext) {
    __shared__ uint4 atile[RPB * 13];   // 13,312 B (12 used + 1 pad per row)
    int tid = threadIdx.x;
    int r0 = blockIdx.x * RPB;

    const u32* hb = reinterpret_cast<const u32*>(rprev);

    // ---- phase 1: aggregate 64 rows (12 lanes x 8 features), 3 clean rounds ----
#pragma unroll
    for (int it = 0; it < 3; ++it) {
        int slot = it * TPB + tid;          // 0..767
        int ln  = slot / 12;
        int sub = slot - ln * 12;
        int v = r0 + ln;
        uint4 res = make_uint4(0u, 0u, 0u, 0u);
        if (v < NN) {
            int co = sub * 4;
            uint4 hv = *reinterpret_cast<const uint4*>(&hb[(size_t)v * FB + co]);
            float a0 = bf_lo(hv.x), a1 = bf_hi(hv.x);
            float a2 = bf_lo(hv.y), a3 = bf_hi(hv.y);
            float a4 = bf_lo(hv.z), a5 = bf_hi(hv.z);
            float a6 = bf_lo(hv.w), a7 = bf_hi(hv.w);   // self term r[v]

            int deg = cnt[v];
            if (deg > CAP) deg = CAP;
            const u16* bkt = &bucket[v * CAP];
            int e = 0;
            for (; e + 7 < deg; e += 8) {
                uint4 b8 = *reinterpret_cast<const uint4*>(&bkt[e]);
                int s0 = b8.x & 0xffff, s1 = b8.x >> 16;
                int s2 = b8.y & 0xffff, s3 = b8.y >> 16;
                int s4 = b8.z & 0xffff, s5 = b8.z >> 16;
                int s6 = b8.w & 0xffff, s7 = b8.w >> 16;
                u32x4 g0 = ld16_sc0(&hb[(size_t)s0 * FB + co]);
                u32x4 g1 = ld16_sc0(&hb[(size_t)s1 * FB + co]);
                u32x4 g2 = ld16_sc0(&hb[(size_t)s2 * FB + co]);
                u32x4 g3 = ld16_sc0(&hb[(size_t)s3 * FB + co]);
                u32x4 g4 = ld16_sc0(&hb[(size_t)s4 * FB + co]);
                u32x4 g5 = ld16_sc0(&hb[(size_t)s5 * FB + co]);
                u32x4 g6 = ld16_sc0(&hb[(size_t)s6 * FB + co]);
                u32x4 g7 = ld16_sc0(&hb[(size_t)s7 * FB + co]);
                gather_fence();
                a0 += bf_lo(g0[0]) + bf_lo(g1[0]) + bf_lo(g2[0]) + bf_lo(g3[0])
                    + bf_lo(g4[0]) + bf_lo(g5[0]) + bf_lo(g6[0]) + bf_lo(g7[0]);
                a1 += bf_hi(g0[0]) + bf_hi(g1[0]) + bf_hi(g2[0]) + bf_hi(g3[0])
                    + bf_hi(g4[0]) + bf_hi(g5[0]) + bf_hi(g6[0]) + bf_hi(g7[0]);
                a2 += bf_lo(g0[1]) + bf_lo(g1[1]) + bf_lo(g2[1]) + bf_lo(g3[1])
                    + bf_lo(g4[1]) + bf_lo(g5[1]) + bf_lo(g6[1]) + bf_lo(g7[1]);
                a3 += bf_hi(g0[1]) + bf_hi(g1[1]) + bf_hi(g2[1]) + bf_hi(g3[1])
                    + bf_hi(g4[1]) + bf_hi(g5[1]) + bf_hi(g6[1]) + bf_hi(g7[1]);
                a4 += bf_lo(g0[2]) + bf_lo(g1[2]) + bf_lo(g2[2]) + bf_lo(g3[2])
                    + bf_lo(g4[2]) + bf_lo(g5[2]) + bf_lo(g6[2]) + bf_lo(g7[2]);
                a5 += bf_hi(g0[2]) + bf_hi(g1[2]) + bf_hi(g2[2]) + bf_hi(g3[2])
                    + bf_hi(g4[2]) + bf_hi(g5[2]) + bf_hi(g6[2]) + bf_hi(g7[2]);
                a6 += bf_lo(g0[3]) + bf_lo(g1[3]) + bf_lo(g2[3]) + bf_lo(g3[3])
                    + bf_lo(g4[3]) + bf_lo(g5[3]) + bf_lo(g6[3]) + bf_lo(g7[3]);
                a7 += bf_hi(g0[3]) + bf_hi(g1[3]) + bf_hi(g2[3]) + bf_hi(g3[3])
                    + bf_hi(g4[3]) + bf_hi(g5[3]) + bf_hi(g6[3]) + bf_hi(g7[3]);
            }
            for (; e + 3 < deg; e += 4) {
                uint2 b4 = *reinterpret_cast<const uint2*>(&bkt[e]);
                int s0 = b4.x & 0xffff, s1 = b4.x >> 16;
                int s2 = b4.y & 0xffff, s3 = b4.y >> 16;
                u32x4 g0 = ld16_sc0(&hb[(size_t)s0 * FB + co]);
                u32x4 g1 = ld16_sc0(&hb[(size_t)s1 * FB + co]);
                u32x4 g2 = ld16_sc0(&hb[(size_t)s2 * FB + co]);
                u32x4 g3 = ld16_sc0(&hb[(size_t)s3 * FB + co]);
                gather_fence();
                a0 += bf_lo(g0[0]) + bf_lo(g1[0]) + bf_lo(g2[0]) + bf_lo(g3[0]);
                a1 += bf_hi(g0[0]) + bf_hi(g1[0]) + bf_hi(g2[0]) + bf_hi(g3[0]);
                a2 += bf_lo(g0[1]) + bf_lo(g1[1]) + bf_lo(g2[1]) + bf_lo(g3[1]);
                a3 += bf_hi(g0[1]) + bf_hi(g1[1]) + bf_hi(g2[1]) + bf_hi(g3[1]);
                a4 += bf_lo(g0[2]) + bf_lo(g1[2]) + bf_lo(g2[2]) + bf_lo(g3[2]);
                a5 += bf_hi(g0[2]) + bf_hi(g1[2]) + bf_hi(g2[2]) + bf_hi(g3[2]);
                a6 += bf_lo(g0[3]) + bf_lo(g1[3]) + bf_lo(g2[3]) + bf_lo(g3[3]);
                a7 += bf_hi(g0[3]) + bf_hi(g1[3]) + bf_hi(g2[3]) + bf_hi(g3[3]);
            }
            for (; e < deg; ++e) {
                int s = bkt[e];
                u32x4 g = ld16_sc0(&hb[(size_t)s * FB + co]);
                gather_fence();
                a0 += bf_lo(g[0]); a1 += bf_hi(g[0]);
                a2 += bf_lo(g[1]); a3 += bf_hi(g[1]);
                a4 += bf_lo(g[2]); a5 += bf_hi(g[2]);
                a6 += bf_lo(g[3]); a7 += bf_hi(g[3]);
            }
            float dv = dis[v];
            res = make_uint4(packbf(dv * a0, dv * a1), packbf(dv * a2, dv * a3),
                             packbf(dv * a4, dv * a5), packbf(dv * a6, dv * a7));
        }
        atile[ln * 13 + sub] = res;
    }
    __syncthreads();

    // ---- phase 2: MFMA (4 waves x 16 rows x 96 cols), B-fragments from global ----
    int wave = tid >> 6;
    int lane = tid & 63;
    int m    = lane & 15;
    int quad = lane >> 4;
    int arow = wave * 16 + m;

    short8 a0 = *reinterpret_cast<const short8*>(&atile[arow * 13 + 0 * 4 + quad]);
    short8 a1 = *reinterpret_cast<const short8*>(&atile[arow * 13 + 1 * 4 + quad]);
    short8 a2 = *reinterpret_cast<const short8*>(&atile[arow * 13 + 2 * 4 + quad]);

    f32x4 acc[6];
#pragma unroll
    for (int ct = 0; ct < 6; ++ct) acc[ct] = (f32x4)(0.0f);
#pragma unroll
    for (int ct = 0; ct < 6; ++ct) {
        short8 b0 = *reinterpret_cast<const short8*>(&wfragG[((ct * 3 + 0) * 4 + quad) * 16 + m]);
        short8 b1 = *reinterpret_cast<const short8*>(&wfragG[((ct * 3 + 1) * 4 + quad) * 16 + m]);
        short8 b2 = *reinterpret_cast<const short8*>(&wfragG[((ct * 3 + 2) * 4 + quad) * 16 + m]);
        acc[ct] = __builtin_amdgcn_mfma_f32_16x16x32_bf16(a0, b0, acc[ct], 0, 0, 0);
        acc[ct] = __builtin_amdgcn_mfma_f32_16x16x32_bf16(a1, b1, acc[ct], 0, 0, 0);
        acc[ct] = __builtin_amdgcn_mfma_f32_16x16x32_bf16(a2, b2, acc[ct], 0, 0, 0);
    }

    // ---- epilogue: h = relu(y + b); store (last ? h : dis[row]*h) ----
    int rbase = r0 + wave * 16 + quad * 4;
    float dr[4];
#pragma unroll
    for (int r = 0; r < 4; ++r) {
        int row = rbase + r;
        dr[r] = (row < NN) ? (last ? 1.0f : dis[row]) : 0.0f;
    }
#pragma unroll
    for (int ct = 0; ct < 6; ++ct) {
        float bb = bias[ct * 16 + m];
#pragma unroll
        for (int r = 0; r < 4; ++r) {
            int row = rbase + r;
            if (row < NN) {
                float h = fmaxf(acc[ct][r] + bb, 0.0f);
                rnext[(size_t)row * F + ct * 16 + m] = (u16)f2bf_rne(h * dr[r]);
            }
        }
    }
}

// ---------------- fused mean pool + FC per graph (batch is sorted) ----------------
__device__ inline int lower_bound_i(const int* __restrict__ a, int n, int key) {
    int lo = 0, hi = n;
    while (lo < hi) {
        int mid = (lo + hi) >> 1;
        if (a[mid] < key) lo = mid + 1; else hi = mid;
    }
    return lo;
}

__global__ __launch_bounds__(512) void k_poolfc(const uint2* __restrict__ hb2,
                                                const int* __restrict__ batch,
                                                const float* __restrict__ fcw,
                                                const float* __restrict__ fcb,
                                                float* __restrict__ out) {
    __shared__ int range[2];
    __shared__ float4 part[PROWS][24];
    __shared__ float pl[F];
    int g = blockIdx.x;
    int t = threadIdx.x;
    if (t == 0) range[0] = lower_bound_i(batch, NN, g);
    if (t == 1) range[1] = lower_bound_i(batch, NN, g + 1);
    __syncthreads();
    int lo = range[0], hi = range[1];
    int row = t / 24;
    int sub = t - row * 24;
    if (row < PROWS) {
        float4 acc = make_float4(0.f, 0.f, 0.f, 0.f);
        for (int v = lo + row; v < hi; v += PROWS) {
            uint2 xv = hb2[(size_t)v * 24 + sub];
            acc.x += bf_lo(xv.x); acc.y += bf_hi(xv.x);
            acc.z += bf_lo(xv.y); acc.w += bf_hi(xv.y);
        }
        part[row][sub] = acc;
    }
    __syncthreads();
    if (t < 24) {
        float4 s = part[0][t];
        for (int r = 1; r < PROWS; ++r) {
            float4 p = part[r][t];
            s.x += p.x; s.y += p.y; s.z += p.z; s.w += p.w;
        }
        float inv = 1.0f / fmaxf((float)(hi - lo), 1.0f);
        pl[t * 4 + 0] = s.x * inv;
        pl[t * 4 + 1] = s.y * inv;
        pl[t * 4 + 2] = s.z * inv;
        pl[t * 4 + 3] = s.w * inv;
    }
    __syncthreads();
    if (t < OD) {
        float acc = 0.0f;
        for (int f = 0; f < F; ++f) acc += pl[f] * fcw[f * OD + t];
        out[g * OD + t] = acc + fcb[t];
    }
}

extern "C" void kernel_launch(void* const* d_in, const int* in_sizes, int n_in,
                              void* d_out, int out_size, void* d_ws, size_t ws_size,
                              hipStream_t stream) {
    (void)in_sizes; (void)n_in; (void)out_size; (void)ws_size;
    const float* x    = (const float*)d_in[0];
    const int*   ei   = (const int*)d_in[1];
    const int*   batc = (const int*)d_in[2];
    const float* W1   = (const float*)d_in[3];
    const float* b1   = (const float*)d_in[4];
    const float* W2   = (const float*)d_in[5];
    const float* b2   = (const float*)d_in[6];
    const float* W3   = (const float*)d_in[7];
    const float* b3   = (const float*)d_in[8];
    const float* fcw  = (const float*)d_in[9];
    const float* fcb  = (const float*)d_in[10];
    float* out = (float*)d_out;

    const int* src = ei;
    const int* tgt = ei + NE;

    char* ws = (char*)d_ws;
    int*    cnt    = (int*)ws;    ws += align_up((size_t)NN * 4);
    float*  dis    = (float*)ws;  ws += align_up((size_t)NN * 4);
    u16*    bucket = (u16*)ws;    ws += align_up((size_t)NN * CAP * 2);   // 6.4 MB
    u32*    ep     = (u32*)ws;    ws += align_up((size_t)NE * 4);         // 3.2 MB
    u32*    rA     = (u32*)ws;    ws += align_up((size_t)NN * FB * 4);    // 9.6 MB
    u32*    rB     = (u32*)ws;    ws += align_up((size_t)NN * FB * 4);    // 9.6 MB
    uint4*  wfrag3 = (uint4*)ws;  ws += align_up((size_t)3 * NWF * 16);   // 55 KB

    const int B = 256;
    const int cvt_grid   = (NN * RB4 + B - 1) / B;
    const int wprep_grid = (3 * NWF + B - 1) / B;
    const int pack_grid  = (NE / 4 + B - 1) / B;
    const int layer_grid = (NN + RPB - 1) / RPB;   // 782

    // ---- bucket build + prep (once per call) ----
    (void)hipMemsetAsync(cnt, 0, (size_t)NN * 4, stream);
    k_pack  <<<pack_grid, B, 0, stream>>>(src, tgt, (uint4*)ep);
    k_fillb <<<SHARDS * PERSHARD, B, 0, stream>>>((const uint4*)ep, cnt, bucket);
    k_wprep3<<<wprep_grid, B, 0, stream>>>(W1, W2, W3, wfrag3);
    k_cvt   <<<cvt_grid, B, 0, stream>>>((const float4*)x, cnt, dis, (uint4*)rA);

    // ---- 3 fused layers ----
    k_layer<<<layer_grid, TPB, 0, stream>>>((const uint4*)rA, wfrag3 + 0 * NWF,
                                            cnt, bucket, dis, b1, 0, (u16*)rB);
    k_layer<<<layer_grid, TPB, 0, stream>>>((const uint4*)rB, wfrag3 + 1 * NWF,
                                            cnt, bucket, dis, b2, 0, (u16*)rA);
    k_layer<<<layer_grid, TPB, 0, stream>>>((const uint4*)rA, wfrag3 + 2 * NWF,
                                            cnt, bucket, dis, b3, 1, (u16*)rB);

    // ---- fused mean pool + FC ----
    k_poolfc<<<NG, 512, 0, stream>>>((const uint2*)rB, batc, fcw, fcb, out);
}